// Round 1
// baseline (245.223 us; speedup 1.0000x reference)
//
#include <hip/hip_runtime.h>
#include <hip/hip_bf16.h>
#include <cstdint>
#include <math.h>

#define BATCH 4
#define SDIM  2048
#define DDIM  1024

typedef __attribute__((ext_vector_type(8))) short bf16x8;
typedef __attribute__((ext_vector_type(4))) float f32x4;

__device__ __forceinline__ float bf2f(unsigned short u) {
  union { unsigned int i; float f; } v; v.i = ((unsigned int)u) << 16; return v.f;
}
__device__ __forceinline__ unsigned short f2bf(float f) {
  unsigned int i = __float_as_uint(f);
  return (unsigned short)((i + 0x7FFFu + ((i >> 16) & 1u)) >> 16);  // RNE
}

#define GLOAD16(gp, lp) \
  __builtin_amdgcn_global_load_lds((const __attribute__((address_space(1))) void*)(gp), \
                                   (__attribute__((address_space(3))) void*)(lp), 16, 0, 0)

// ---------------- fp32 -> bf16 convert ----------------
__global__ void cvt_f32_bf16(const float* __restrict__ in,
                             unsigned short* __restrict__ out, int n) {
  int i0 = (blockIdx.x * 256 + threadIdx.x) * 4;
  int stride = gridDim.x * 256 * 4;
  for (int i = i0; i < n; i += stride) {
    float4 v = *reinterpret_cast<const float4*>(in + i);
    ushort4 o;
    o.x = f2bf(v.x); o.y = f2bf(v.y); o.z = f2bf(v.z); o.w = f2bf(v.w);
    *reinterpret_cast<ushort4*>(out + i) = o;
  }
}

// ---------------- templated MFMA GEMM (m97 structure) ----------------
// All operands NT: C[m,n] = sum_k A[m,k]*B[n,k]; A,B row-major bf16, K contiguous.
// MODE 0: projections: A=xb[8192,1024], B=W[1024,1024], C=bf16[8192,1024] + bias
// MODE 1: output proj: same shapes, C=f32 + bias
// MODE 2: scores: per-batch, triangular grid: C = bf16(|Q@K^T| * 1/32), causal
// MODE 3: PV: per-batch, A=P[b][2048,2048], B=Vt[b][1024,2048], K truncated to (ti+1)*128
template<int MODE>
__global__ __launch_bounds__(256, 2)
void gemm_kernel(const unsigned short* __restrict__ A,
                 const unsigned short* __restrict__ B,
                 const float* __restrict__ bias,
                 void* __restrict__ C)
{
  __shared__ unsigned short As[128 * 32];
  __shared__ unsigned short Bs[128 * 32];

  const int tid  = threadIdx.x;
  const int wave = tid >> 6;
  const int lane = tid & 63;
  const int wr   = wave >> 1;   // wave row (0..1), wave covers 64x64
  const int wc   = wave & 1;    // wave col

  const unsigned short *Ab, *Bb;
  int lda, ldb, ktiles;
  int ti, tj, bz = 0;

  if constexpr (MODE == 0 || MODE == 1) {
    ti = blockIdx.x; tj = blockIdx.y;
    Ab = A + (size_t)ti * 128 * DDIM;  lda = DDIM;
    Bb = B + (size_t)tj * 128 * DDIM;  ldb = DDIM;
    ktiles = DDIM / 32;
  } else if constexpr (MODE == 2) {
    int t = blockIdx.x; bz = blockIdx.y;
    ti = 0;
    while ((ti + 1) * (ti + 2) / 2 <= t) ++ti;   // triangular decode (<=16 iters)
    tj = t - ti * (ti + 1) / 2;                  // tj <= ti
    Ab = A + (size_t)bz * SDIM * DDIM + (size_t)ti * 128 * DDIM; lda = DDIM;
    Bb = B + (size_t)bz * SDIM * DDIM + (size_t)tj * 128 * DDIM; ldb = DDIM;
    ktiles = DDIM / 32;
  } else { // MODE 3
    bz = blockIdx.y;
    ti = blockIdx.x >> 3;        // q-row tile 0..15
    tj = blockIdx.x & 7;         // out-col tile 0..7
    Ab = A + (size_t)bz * SDIM * SDIM + (size_t)ti * 128 * SDIM; lda = SDIM;
    Bb = B + (size_t)bz * DDIM * SDIM + (size_t)tj * 128 * SDIM; ldb = SDIM;
    ktiles = (ti + 1) * 4;       // causal: only K < (ti+1)*128
  }

  f32x4 acc[4][4];
#pragma unroll
  for (int i = 0; i < 4; ++i)
#pragma unroll
    for (int j = 0; j < 4; ++j) acc[i][j] = (f32x4){0.f, 0.f, 0.f, 0.f};

  // staging: tile is 128 rows x 32 cols bf16 = 8KB = 512 x 16B chunks.
  // chunk c -> row c>>2, byte (c&3)*16. Thread t handles chunks t and t+256.
  const int ar0 = tid >> 2;            // rows 0..63
  const int ak0 = (tid & 3) * 8;       // bf16 elems within row
  // frag read coords
  const int fr = lane & 15;
  const int fk = (lane >> 4) * 8;

  for (int kt = 0; kt < ktiles; ++kt) {
    const size_t ka = (size_t)kt * 32;
    GLOAD16(Ab + (size_t)ar0 * lda + ka + ak0,        As + wave * 512);
    GLOAD16(Ab + (size_t)(ar0 + 64) * lda + ka + ak0, As + 2048 + wave * 512);
    GLOAD16(Bb + (size_t)ar0 * ldb + ka + ak0,        Bs + wave * 512);
    GLOAD16(Bb + (size_t)(ar0 + 64) * ldb + ka + ak0, Bs + 2048 + wave * 512);
    __syncthreads();   // drains vmcnt -> tile resident

    bf16x8 af[4], bf[4];
#pragma unroll
    for (int mi = 0; mi < 4; ++mi)
      af[mi] = *reinterpret_cast<const bf16x8*>(As + (wr * 64 + mi * 16 + fr) * 32 + fk);
#pragma unroll
    for (int ni = 0; ni < 4; ++ni)
      bf[ni] = *reinterpret_cast<const bf16x8*>(Bs + (wc * 64 + ni * 16 + fr) * 32 + fk);
#pragma unroll
    for (int mi = 0; mi < 4; ++mi)
#pragma unroll
      for (int ni = 0; ni < 4; ++ni)
        acc[mi][ni] = __builtin_amdgcn_mfma_f32_16x16x32_bf16(af[mi], bf[ni], acc[mi][ni], 0, 0, 0);
    __syncthreads();   // all waves done reading before next stage overwrites
  }

  // epilogue: C/D layout col = lane&15, row = (lane>>4)*4 + r
  const int row0 = wr * 64, col0 = wc * 64;
#pragma unroll
  for (int mi = 0; mi < 4; ++mi) {
#pragma unroll
    for (int ni = 0; ni < 4; ++ni) {
#pragma unroll
      for (int r = 0; r < 4; ++r) {
        const int lr = row0 + mi * 16 + (lane >> 4) * 4 + r;
        const int lc = col0 + ni * 16 + (lane & 15);
        const float v = acc[mi][ni][r];
        if constexpr (MODE == 0) {
          const int gr = ti * 128 + lr, gc = tj * 128 + lc;
          ((unsigned short*)C)[(size_t)gr * DDIM + gc] = f2bf(v + bias[gc]);
        } else if constexpr (MODE == 1) {
          const int gr = ti * 128 + lr, gc = tj * 128 + lc;
          ((float*)C)[(size_t)gr * DDIM + gc] = v + bias[gc];
        } else if constexpr (MODE == 2) {
          const int gi = ti * 128 + lr, gj = tj * 128 + lc;
          float s = fabsf(v) * 0.03125f;           // |q.k| / sqrt(1024)
          if (gj > gi) s = -INFINITY;               // strictly-above diag (diag tiles only)
          ((unsigned short*)C)[(size_t)bz * SDIM * SDIM + (size_t)gi * SDIM + gj] = f2bf(s);
        } else {
          const int gi = ti * 128 + lr, gd = tj * 128 + lc;
          ((unsigned short*)C)[(size_t)bz * SDIM * DDIM + (size_t)gi * DDIM + gd] = f2bf(v);
        }
      }
    }
  }
}

// ---------------- row softmax over causal length, zero-pad to tile boundary ----------------
__global__ void softmax_rows(unsigned short* __restrict__ Sc) {
  const int rid = blockIdx.x;            // 0 .. BATCH*SDIM-1
  const int b = rid >> 11, i = rid & (SDIM - 1);
  unsigned short* row = Sc + ((size_t)b * SDIM + i) * SDIM;
  const int L    = i + 1;
  const int Lpad = ((i >> 7) + 1) << 7;  // next 128 boundary
  const int tid  = threadIdx.x;

  float m = 0.0f;                        // all valid values are |s| >= 0
  for (int j = tid; j < L; j += 256) m = fmaxf(m, bf2f(row[j]));
#pragma unroll
  for (int off = 32; off; off >>= 1) m = fmaxf(m, __shfl_down(m, off));
  __shared__ float redm[4];
  if ((tid & 63) == 0) redm[tid >> 6] = m;
  __syncthreads();
  const float M = fmaxf(fmaxf(redm[0], redm[1]), fmaxf(redm[2], redm[3]));

  float s = 0.0f;
  for (int j = tid; j < L; j += 256) s += expf(bf2f(row[j]) - M);
#pragma unroll
  for (int off = 32; off; off >>= 1) s += __shfl_down(s, off);
  __shared__ float reds[4];
  if ((tid & 63) == 0) reds[tid >> 6] = s;
  __syncthreads();
  const float inv = 1.0f / (reds[0] + reds[1] + reds[2] + reds[3]);

  for (int j = tid; j < Lpad; j += 256) {
    float p = (j < L) ? expf(bf2f(row[j]) - M) * inv : 0.0f;
    row[j] = f2bf(p);   // in-place: each index read/written by the same thread
  }
}

// ---------------- bf16 transpose [rows,cols] -> [cols,rows], per batch ----------------
__global__ void transpose_bf16(const unsigned short* __restrict__ in,
                               unsigned short* __restrict__ out,
                               int rows, int cols) {
  __shared__ unsigned short tile[64][65];
  const int b = blockIdx.z;
  in  += (size_t)b * rows * cols;
  out += (size_t)b * rows * cols;
  const int tx = threadIdx.x & 63;
  const int ty = threadIdx.x >> 6;
  const int r0 = blockIdx.y * 64;   // input row tile
  const int c0 = blockIdx.x * 64;   // input col tile
  for (int r = ty; r < 64; r += 4)
    tile[r][tx] = in[(size_t)(r0 + r) * cols + c0 + tx];
  __syncthreads();
  for (int r = ty; r < 64; r += 4)
    out[(size_t)(c0 + r) * rows + r0 + tx] = tile[tx][r];
}

// ---------------- host launch ----------------
extern "C" void kernel_launch(void* const* d_in, const int* in_sizes, int n_in,
                              void* d_out, int out_size, void* d_ws, size_t ws_size,
                              hipStream_t stream) {
  const float* x  = (const float*)d_in[0];
  const float* Wq = (const float*)d_in[1];
  const float* bq = (const float*)d_in[2];
  const float* Wk = (const float*)d_in[3];
  const float* bk = (const float*)d_in[4];
  const float* Wv = (const float*)d_in[5];
  const float* bv = (const float*)d_in[6];
  const float* Wo = (const float*)d_in[7];
  const float* bo = (const float*)d_in[8];
  float* out = (float*)d_out;

  const size_t NTOK = (size_t)BATCH * SDIM;       // 8192
  unsigned short* ws = (unsigned short*)d_ws;
  unsigned short* xb = ws;                        // [8192,1024]
  unsigned short* wq = xb + NTOK * DDIM;          // [1024,1024] each
  unsigned short* wk = wq + (size_t)DDIM * DDIM;
  unsigned short* wv = wk + (size_t)DDIM * DDIM;
  unsigned short* wo = wv + (size_t)DDIM * DDIM;
  unsigned short* Qb = wo + (size_t)DDIM * DDIM;  // [B*S,1024]
  unsigned short* Kb = Qb + NTOK * DDIM;
  unsigned short* Vb = Kb + NTOK * DDIM;
  unsigned short* Vt = Vb + NTOK * DDIM;          // [B,1024,2048]
  unsigned short* Ob = Vt + NTOK * DDIM;          // [B*S,1024]
  unsigned short* Sc = Ob + NTOK * DDIM;          // [B,2048,2048] scores->P

  const int NX = (int)(NTOK * DDIM);              // 8M
  const int NW = DDIM * DDIM;                     // 1M

  cvt_f32_bf16<<<2048, 256, 0, stream>>>(x,  xb, NX);
  cvt_f32_bf16<<<256,  256, 0, stream>>>(Wq, wq, NW);
  cvt_f32_bf16<<<256,  256, 0, stream>>>(Wk, wk, NW);
  cvt_f32_bf16<<<256,  256, 0, stream>>>(Wv, wv, NW);
  cvt_f32_bf16<<<256,  256, 0, stream>>>(Wo, wo, NW);

  // Q,K,V projections
  gemm_kernel<0><<<dim3(64, 8), 256, 0, stream>>>(xb, wq, bq, Qb);
  gemm_kernel<0><<<dim3(64, 8), 256, 0, stream>>>(xb, wk, bk, Kb);
  gemm_kernel<0><<<dim3(64, 8), 256, 0, stream>>>(xb, wv, bv, Vb);

  // scores (lower-triangular tiles only): Sc = bf16(|Q@K^T|/32)
  gemm_kernel<2><<<dim3(136, BATCH), 256, 0, stream>>>(Qb, Kb, nullptr, Sc);

  // row softmax (in place, zero-padded to 128 boundary)
  softmax_rows<<<BATCH * SDIM, 256, 0, stream>>>(Sc);

  // V transpose for NT PV gemm
  transpose_bf16<<<dim3(DDIM / 64, SDIM / 64, BATCH), 256, 0, stream>>>(Vb, Vt, SDIM, DDIM);

  // O = P @ V  (causal-truncated K)
  gemm_kernel<3><<<dim3(128, BATCH), 256, 0, stream>>>(Sc, Vt, nullptr, Ob);

  // final projection -> fp32 out
  gemm_kernel<1><<<dim3(64, 8), 256, 0, stream>>>(Ob, wo, bo, out);
}

// Round 2
// 220.492 us; speedup vs baseline: 1.1122x; 1.1122x over previous
//
#include <hip/hip_runtime.h>
#include <hip/hip_bf16.h>
#include <cstdint>
#include <math.h>

#define BATCH 4
#define SDIM  2048
#define DDIM  1024
#define QKVN  3072   // fused Q|K|V output width

typedef __attribute__((ext_vector_type(8))) short bf16x8;
typedef __attribute__((ext_vector_type(8))) unsigned short u16x8;
typedef __attribute__((ext_vector_type(4))) float f32x4;

__device__ __forceinline__ float bf2f(unsigned short u) {
  union { unsigned int i; float f; } v; v.i = ((unsigned int)u) << 16; return v.f;
}
__device__ __forceinline__ unsigned short f2bf(float f) {
  unsigned int i = __float_as_uint(f);
  return (unsigned short)((i + 0x7FFFu + ((i >> 16) & 1u)) >> 16);  // RNE
}

#define GLOAD16(gp, lp) \
  __builtin_amdgcn_global_load_lds((const __attribute__((address_space(1))) void*)(gp), \
                                   (__attribute__((address_space(3))) void*)(lp), 16, 0, 0)

// ---------------- fp32 -> bf16 convert ----------------
__global__ void cvt_f32_bf16(const float* __restrict__ in,
                             unsigned short* __restrict__ out, int n) {
  int i0 = (blockIdx.x * 256 + threadIdx.x) * 4;
  int stride = gridDim.x * 256 * 4;
  for (int i = i0; i < n; i += stride) {
    float4 v = *reinterpret_cast<const float4*>(in + i);
    ushort4 o;
    o.x = f2bf(v.x); o.y = f2bf(v.y); o.z = f2bf(v.z); o.w = f2bf(v.w);
    *reinterpret_cast<ushort4*>(out + i) = o;
  }
}

// ---------------- templated MFMA GEMM, 2-phase double-buffered ----------------
// NT: C[m,n] = sum_k A[m,k]*B[n,k]; A,B row-major bf16, K contiguous.
// MODE 0: fused QKV: A=xb[8192,1024], B=Wqkv[3072,1024], C=bf16[8192,3072] + bias(sel)
// MODE 1: out proj:  A=Ob[8192,1024], B=Wo[1024,1024],   C=f32[8192,1024] + bias
// MODE 2: scores: per-batch, triangular grid; A=Q sec, B=K sec of QKVb (ld 3072)
// MODE 3: PV: per-batch, A=P[b][2048,2048], B=Vt[b][1024,2048], K truncated
template<int MODE>
__global__ __launch_bounds__(256, 3)
void gemm_kernel(const unsigned short* __restrict__ A,
                 const unsigned short* __restrict__ B,
                 const float* __restrict__ bias0,
                 const float* __restrict__ bias1,
                 const float* __restrict__ bias2,
                 void* __restrict__ C)
{
  __shared__ unsigned short As[2][128 * 32];
  __shared__ unsigned short Bs[2][128 * 32];

  const int tid  = threadIdx.x;
  const int wave = tid >> 6;
  const int lane = tid & 63;
  const int wr   = wave >> 1;   // wave row (0..1), wave covers 64x64
  const int wc   = wave & 1;    // wave col

  const unsigned short *Ab, *Bb;
  int lda, ldb, ktiles;
  int ti, tj, bz = 0;

  if constexpr (MODE == 0) {
    ti = blockIdx.x; tj = blockIdx.y;
    Ab = A + (size_t)ti * 128 * DDIM;  lda = DDIM;
    Bb = B + (size_t)tj * 128 * DDIM;  ldb = DDIM;
    ktiles = DDIM / 32;
  } else if constexpr (MODE == 1) {
    ti = blockIdx.x; tj = blockIdx.y;
    Ab = A + (size_t)ti * 128 * DDIM;  lda = DDIM;
    Bb = B + (size_t)tj * 128 * DDIM;  ldb = DDIM;
    ktiles = DDIM / 32;
  } else if constexpr (MODE == 2) {
    int t = blockIdx.x; bz = blockIdx.y;
    ti = 0;
    while ((ti + 1) * (ti + 2) / 2 <= t) ++ti;   // triangular decode
    tj = t - ti * (ti + 1) / 2;                  // tj <= ti
    Ab = A + (size_t)bz * SDIM * QKVN + (size_t)ti * 128 * QKVN;        lda = QKVN; // Q section
    Bb = A + (size_t)bz * SDIM * QKVN + (size_t)tj * 128 * QKVN + 1024; ldb = QKVN; // K section
    ktiles = DDIM / 32;
  } else { // MODE 3
    bz = blockIdx.y;
    ti = blockIdx.x >> 3;        // q-row tile 0..15
    tj = blockIdx.x & 7;         // out-col tile 0..7
    Ab = A + (size_t)bz * SDIM * SDIM + (size_t)ti * 128 * SDIM; lda = SDIM;
    Bb = B + (size_t)bz * DDIM * SDIM + (size_t)tj * 128 * SDIM; ldb = SDIM;
    ktiles = (ti + 1) * 4;       // causal: only K < (ti+1)*128
  }

  f32x4 acc[4][4];
#pragma unroll
  for (int i = 0; i < 4; ++i)
#pragma unroll
    for (int j = 0; j < 4; ++j) acc[i][j] = (f32x4){0.f, 0.f, 0.f, 0.f};

  const int ar0 = tid >> 2;            // rows 0..63
  const int ak0 = (tid & 3) * 8;       // bf16 elems within row
  const int fr = lane & 15;
  const int fk = (lane >> 4) * 8;

#define STAGE(buf, kt) do {                                                  \
    const size_t ka_ = (size_t)(kt) * 32 + ak0;                              \
    GLOAD16(Ab + (size_t)ar0 * lda + ka_,        &As[buf][wave * 512]);       \
    GLOAD16(Ab + (size_t)(ar0 + 64) * lda + ka_, &As[buf][2048 + wave * 512]);\
    GLOAD16(Bb + (size_t)ar0 * ldb + ka_,        &Bs[buf][wave * 512]);       \
    GLOAD16(Bb + (size_t)(ar0 + 64) * ldb + ka_, &Bs[buf][2048 + wave * 512]);\
  } while (0)

  STAGE(0, 0);
  __syncthreads();              // drains vmcnt -> buf0 resident
  int cur = 0;

  for (int kt = 0; kt < ktiles; ++kt) {
    if (kt + 1 < ktiles) STAGE(cur ^ 1, kt + 1);   // prefetch overlaps compute

    bf16x8 af[4], bfv[4];
#pragma unroll
    for (int mi = 0; mi < 4; ++mi)
      af[mi] = *reinterpret_cast<const bf16x8*>(&As[cur][(wr * 64 + mi * 16 + fr) * 32 + fk]);
#pragma unroll
    for (int ni = 0; ni < 4; ++ni)
      bfv[ni] = *reinterpret_cast<const bf16x8*>(&Bs[cur][(wc * 64 + ni * 16 + fr) * 32 + fk]);
#pragma unroll
    for (int mi = 0; mi < 4; ++mi)
#pragma unroll
      for (int ni = 0; ni < 4; ++ni)
        acc[mi][ni] = __builtin_amdgcn_mfma_f32_16x16x32_bf16(af[mi], bfv[ni], acc[mi][ni], 0, 0, 0);

    __syncthreads();            // drains prefetch (vmcnt) + everyone's ds_reads
    cur ^= 1;
  }
#undef STAGE

  // epilogue: C/D layout col = lane&15, row = (lane>>4)*4 + r
  const int row0 = wr * 64, col0 = wc * 64;
  const float* bp = bias0;
  if constexpr (MODE == 0) bp = (tj < 8) ? bias0 : ((tj < 16) ? bias1 : bias2);
#pragma unroll
  for (int mi = 0; mi < 4; ++mi) {
#pragma unroll
    for (int ni = 0; ni < 4; ++ni) {
#pragma unroll
      for (int r = 0; r < 4; ++r) {
        const int lr = row0 + mi * 16 + (lane >> 4) * 4 + r;
        const int lc = col0 + ni * 16 + (lane & 15);
        const float v = acc[mi][ni][r];
        if constexpr (MODE == 0) {
          const int gr = ti * 128 + lr, gc = tj * 128 + lc;
          ((unsigned short*)C)[(size_t)gr * QKVN + gc] = f2bf(v + bp[gc & 1023]);
        } else if constexpr (MODE == 1) {
          const int gr = ti * 128 + lr, gc = tj * 128 + lc;
          ((float*)C)[(size_t)gr * DDIM + gc] = v + bp[gc];
        } else if constexpr (MODE == 2) {
          const int gi = ti * 128 + lr, gj = tj * 128 + lc;
          float s = fabsf(v) * 0.03125f;            // |q.k| / sqrt(1024)
          if (gj > gi) s = -INFINITY;               // strictly-above diag (diag tiles)
          ((unsigned short*)C)[(size_t)bz * SDIM * SDIM + (size_t)gi * SDIM + gj] = f2bf(s);
        } else {
          const int gi = ti * 128 + lr, gd = tj * 128 + lc;
          ((unsigned short*)C)[(size_t)bz * SDIM * DDIM + (size_t)gi * DDIM + gd] = f2bf(v);
        }
      }
    }
  }
}

// ---------------- one-pass vectorized row softmax ----------------
// Row i: entries [0, L=i+1) are |s|>=0; [L, Lpad) are -inf (written by MODE 2
// diagonal tiles) -> exp gives exact 0, which MODE 3 requires for padding.
__global__ void softmax_rows(unsigned short* __restrict__ Sc) {
  const int rid = blockIdx.x;            // 0 .. BATCH*SDIM-1
  const int b = rid >> 11, i = rid & (SDIM - 1);
  unsigned short* row = Sc + ((size_t)b * SDIM + i) * SDIM;
  const int Lpad = ((i >> 7) + 1) << 7;  // next 128 boundary
  const int tid  = threadIdx.x;
  const bool act = tid * 8 < Lpad;

  float v[8];
  float m = 0.0f;                        // row max >= 0 always
  if (act) {
    u16x8 u = *reinterpret_cast<const u16x8*>(row + tid * 8);
#pragma unroll
    for (int e = 0; e < 8; ++e) { v[e] = bf2f(u[e]); m = fmaxf(m, v[e]); }
  }
#pragma unroll
  for (int off = 32; off; off >>= 1) m = fmaxf(m, __shfl_down(m, off));
  __shared__ float redm[4], reds[4];
  if ((tid & 63) == 0) redm[tid >> 6] = m;
  __syncthreads();
  const float M = fmaxf(fmaxf(redm[0], redm[1]), fmaxf(redm[2], redm[3]));

  float s = 0.0f;
  if (act) {
#pragma unroll
    for (int e = 0; e < 8; ++e) { v[e] = expf(v[e] - M); s += v[e]; }  // -inf -> 0
  }
#pragma unroll
  for (int off = 32; off; off >>= 1) s += __shfl_down(s, off);
  if ((tid & 63) == 0) reds[tid >> 6] = s;
  __syncthreads();
  const float inv = 1.0f / (reds[0] + reds[1] + reds[2] + reds[3]);

  if (act) {
    ushort4 o0, o1;
    o0.x = f2bf(v[0] * inv); o0.y = f2bf(v[1] * inv);
    o0.z = f2bf(v[2] * inv); o0.w = f2bf(v[3] * inv);
    o1.x = f2bf(v[4] * inv); o1.y = f2bf(v[5] * inv);
    o1.z = f2bf(v[6] * inv); o1.w = f2bf(v[7] * inv);
    *reinterpret_cast<ushort4*>(row + tid * 8)     = o0;
    *reinterpret_cast<ushort4*>(row + tid * 8 + 4) = o1;
  }
}

// ---------------- bf16 transpose: V section of QKVb -> Vt[B,1024,2048] ----------------
__global__ void transpose_v(const unsigned short* __restrict__ qkv,
                            unsigned short* __restrict__ out) {
  __shared__ unsigned short tile[64][65];
  const int b = blockIdx.z;
  const unsigned short* in = qkv + (size_t)b * SDIM * QKVN + 2048;  // V section
  unsigned short* o = out + (size_t)b * DDIM * SDIM;
  const int tx = threadIdx.x & 63;
  const int ty = threadIdx.x >> 6;
  const int r0 = blockIdx.y * 64;   // token tile
  const int c0 = blockIdx.x * 64;   // v-dim tile
  for (int r = ty; r < 64; r += 4)
    tile[r][tx] = in[(size_t)(r0 + r) * QKVN + c0 + tx];
  __syncthreads();
  for (int r = ty; r < 64; r += 4)
    o[(size_t)(c0 + r) * SDIM + r0 + tx] = tile[tx][r];
}

// ---------------- host launch ----------------
extern "C" void kernel_launch(void* const* d_in, const int* in_sizes, int n_in,
                              void* d_out, int out_size, void* d_ws, size_t ws_size,
                              hipStream_t stream) {
  const float* x  = (const float*)d_in[0];
  const float* Wq = (const float*)d_in[1];
  const float* bq = (const float*)d_in[2];
  const float* Wk = (const float*)d_in[3];
  const float* bk = (const float*)d_in[4];
  const float* Wv = (const float*)d_in[5];
  const float* bv = (const float*)d_in[6];
  const float* Wo = (const float*)d_in[7];
  const float* bo = (const float*)d_in[8];
  float* out = (float*)d_out;

  const size_t NTOK = (size_t)BATCH * SDIM;       // 8192
  unsigned short* ws = (unsigned short*)d_ws;
  unsigned short* xb   = ws;                          // [8192,1024]
  unsigned short* wqkv = xb + NTOK * DDIM;            // [3072,1024]
  unsigned short* wo   = wqkv + (size_t)QKVN * DDIM;  // [1024,1024]
  unsigned short* QKVb = wo + (size_t)DDIM * DDIM;    // [8192,3072]
  unsigned short* Vt   = QKVb + NTOK * QKVN;          // [B,1024,2048]
  unsigned short* Ob   = Vt + NTOK * DDIM;            // [8192,1024]
  unsigned short* Sc   = Ob + NTOK * DDIM;            // [B,2048,2048]

  const int NX = (int)(NTOK * DDIM);              // 8M
  const int NW = DDIM * DDIM;                     // 1M

  cvt_f32_bf16<<<2048, 256, 0, stream>>>(x,  xb, NX);
  cvt_f32_bf16<<<256,  256, 0, stream>>>(Wq, wqkv,          NW);
  cvt_f32_bf16<<<256,  256, 0, stream>>>(Wk, wqkv + NW,     NW);
  cvt_f32_bf16<<<256,  256, 0, stream>>>(Wv, wqkv + 2 * NW, NW);
  cvt_f32_bf16<<<256,  256, 0, stream>>>(Wo, wo, NW);

  // fused QKV projection -> QKVb [8192, 3072]
  gemm_kernel<0><<<dim3(64, 24), 256, 0, stream>>>(xb, wqkv, bq, bk, bv, QKVb);

  // scores (lower-triangular tiles): Sc = bf16(|Q@K^T|/32), -inf above diag
  gemm_kernel<2><<<dim3(136, BATCH), 256, 0, stream>>>(QKVb, nullptr, nullptr, nullptr, nullptr, Sc);

  // one-pass softmax (in place; padding becomes exact 0)
  softmax_rows<<<BATCH * SDIM, 256, 0, stream>>>(Sc);

  // V transpose for NT PV gemm
  transpose_v<<<dim3(DDIM / 64, SDIM / 64, BATCH), 256, 0, stream>>>(QKVb, Vt);

  // O = P @ V (causal-truncated K)
  gemm_kernel<3><<<dim3(128, BATCH), 256, 0, stream>>>(Sc, Vt, nullptr, nullptr, nullptr, Ob);

  // final projection -> fp32 out
  gemm_kernel<1><<<dim3(64, 8), 256, 0, stream>>>(Ob, wo, bo, nullptr, nullptr, out);
}

// Round 3
// 209.610 us; speedup vs baseline: 1.1699x; 1.0519x over previous
//
#include <hip/hip_runtime.h>
#include <hip/hip_bf16.h>
#include <cstdint>
#include <math.h>

#define BATCH 4
#define SDIM  2048
#define DDIM  1024
#define QKVN  3072   // fused Q|K|V output width

typedef __attribute__((ext_vector_type(8))) short bf16x8;
typedef __attribute__((ext_vector_type(8))) unsigned short u16x8;
typedef __attribute__((ext_vector_type(4))) float f32x4;

__device__ __forceinline__ float bf2f(unsigned short u) {
  union { unsigned int i; float f; } v; v.i = ((unsigned int)u) << 16; return v.f;
}
__device__ __forceinline__ unsigned short f2bf(float f) {
  unsigned int i = __float_as_uint(f);
  return (unsigned short)((i + 0x7FFFu + ((i >> 16) & 1u)) >> 16);  // RNE
}

#define GLOAD16(gp, lp) \
  __builtin_amdgcn_global_load_lds((const __attribute__((address_space(1))) void*)(gp), \
                                   (__attribute__((address_space(3))) void*)(lp), 16, 0, 0)

// ---------------- fp32 -> bf16 convert (single src) ----------------
__global__ void cvt_f32_bf16(const float* __restrict__ in,
                             unsigned short* __restrict__ out, int n) {
  int i0 = (blockIdx.x * 256 + threadIdx.x) * 4;
  int stride = gridDim.x * 256 * 4;
  for (int i = i0; i < n; i += stride) {
    float4 v = *reinterpret_cast<const float4*>(in + i);
    ushort4 o;
    o.x = f2bf(v.x); o.y = f2bf(v.y); o.z = f2bf(v.z); o.w = f2bf(v.w);
    *reinterpret_cast<ushort4*>(out + i) = o;
  }
}

// 4 weight matrices (1M elems each) in one dispatch; dsts are contiguous slabs.
__global__ void cvt_weights(const float* __restrict__ s0, const float* __restrict__ s1,
                            const float* __restrict__ s2, const float* __restrict__ s3,
                            unsigned short* __restrict__ out) {
  const int NW = DDIM * DDIM;
  const float* src = (blockIdx.y == 0) ? s0 : (blockIdx.y == 1) ? s1
                    : (blockIdx.y == 2) ? s2 : s3;
  unsigned short* dst = out + (size_t)blockIdx.y * NW;
  int i0 = (blockIdx.x * 256 + threadIdx.x) * 4;
  int stride = gridDim.x * 256 * 4;
  for (int i = i0; i < NW; i += stride) {
    float4 v = *reinterpret_cast<const float4*>(src + i);
    ushort4 o;
    o.x = f2bf(v.x); o.y = f2bf(v.y); o.z = f2bf(v.z); o.w = f2bf(v.w);
    *reinterpret_cast<ushort4*>(dst + i) = o;
  }
}

// ---------------- MFMA GEMM: 128x128 tile, BK=32, TRI-buffered, counted vmcnt ----
// NT: C[m,n] = sum_k A[m,k]*B[n,k]; A,B row-major bf16, K contiguous.
// LDS tile layout (per matrix, per buffer): 128 rows x 32 cols bf16 = 8 KB,
// stored in 16B granules with row-pair swizzle:
//   unit u = row>>1 (128 B), logical granule g = (row&1)*4 + slot (slot = 16B col),
//   physical granule p = g ^ (u & 7).   byte = u*128 + p*16.
// Frag reads (ds_read_b128) are then exactly the 8-cycle b128 minimum (no
// conflicts); staging uses the inverse mapping on the per-lane GLOBAL address
// while the LDS destination stays linear (global_load_lds requirement).
//
// K-loop: tile t in buf[t%3]; iter t stages tile t+2, computes tile t, then
// waits vmcnt(4) (drains tile t+1's 4 loads; t+2's 4 stay in flight) + raw
// s_barrier. Load latency is hidden across a full K-tile of MFMA.
//
// MODE 0: fused QKV: A=xb[8192,1024], B=Wqkv[3072,1024], C=bf16[8192,3072]+bias
// MODE 1: out proj:  A=Ob[8192,1024], B=Wo[1024,1024],   C=f32[8192,1024]+bias
// MODE 2: scores: per-batch triangular grid; A=Q sec, B=K sec of QKVb (ld 3072)
// MODE 3: PV: per-batch, A=P[b][2048,2048], B=Vt[b][1024,2048], K truncated
template<int MODE>
__global__ __launch_bounds__(256, 3)
void gemm_kernel(const unsigned short* __restrict__ A,
                 const unsigned short* __restrict__ B,
                 const float* __restrict__ bias0,
                 const float* __restrict__ bias1,
                 const float* __restrict__ bias2,
                 void* __restrict__ C)
{
  __shared__ unsigned short As[3][128 * 32];   // 3 x 8 KB
  __shared__ unsigned short Bs[3][128 * 32];   // 3 x 8 KB

  const int tid  = threadIdx.x;
  const int wave = tid >> 6;
  const int lane = tid & 63;
  const int wr   = wave >> 1;   // wave row (0..1), wave covers 64x64 of C
  const int wc   = wave & 1;    // wave col

  const unsigned short *Ab, *Bb;
  int lda, ldb, ktiles;
  int ti, tj, bz = 0;

  if constexpr (MODE == 0 || MODE == 1) {
    ti = blockIdx.x; tj = blockIdx.y;
    Ab = A + (size_t)ti * 128 * DDIM;  lda = DDIM;
    Bb = B + (size_t)tj * 128 * DDIM;  ldb = DDIM;
    ktiles = DDIM / 32;
  } else if constexpr (MODE == 2) {
    int t = blockIdx.x; bz = blockIdx.y;
    ti = 0;
    while ((ti + 1) * (ti + 2) / 2 <= t) ++ti;   // triangular decode
    tj = t - ti * (ti + 1) / 2;                  // tj <= ti
    Ab = A + (size_t)bz * SDIM * QKVN + (size_t)ti * 128 * QKVN;        lda = QKVN; // Q
    Bb = A + (size_t)bz * SDIM * QKVN + (size_t)tj * 128 * QKVN + 1024; ldb = QKVN; // K
    ktiles = DDIM / 32;
  } else { // MODE 3
    bz = blockIdx.y;
    ti = blockIdx.x >> 3;        // q-row tile 0..15
    tj = blockIdx.x & 7;         // out-col tile 0..7
    Ab = A + (size_t)bz * SDIM * SDIM + (size_t)ti * 128 * SDIM; lda = SDIM;
    Bb = B + (size_t)bz * DDIM * SDIM + (size_t)tj * 128 * SDIM; ldb = SDIM;
    ktiles = (ti + 1) * 4;       // causal: only K < (ti+1)*128
  }

  f32x4 acc[4][4];
#pragma unroll
  for (int i = 0; i < 4; ++i)
#pragma unroll
    for (int j = 0; j < 4; ++j) acc[i][j] = (f32x4){0.f, 0.f, 0.f, 0.f};

  // ---- staging source coords (inverse swizzle), per lane ----
  // chunk c (1 KB = 8 units = rows [16c,16c+16)): lane l writes phys granule
  // (u_loc = l>>3, p = l&7); logical g = p ^ u_loc  (chunk base unit is mult of 8)
  const int g0   = (lane & 7) ^ (lane >> 3);
  const int rloc = 2 * (lane >> 3) + (g0 >> 2);   // row within 16-row chunk
  const int colg = (g0 & 3) * 8;                  // bf16 elem offset within 32-col K-tile

  // ---- fragment read offsets (swizzled), per lane ----
  // logical (row = base + m*16 + fr, slot s): u = row>>1, g = (fr&1)*4+s,
  // p = g ^ ((fr>>1)&7); elem = u*64 + p*8.
  const int s_  = lane >> 4;
  const int fr  = lane & 15;
  const int p_  = (((fr & 1) << 2) | s_) ^ ((fr >> 1) & 7);
  const int fA  = wr * 2048 + (fr >> 1) * 64 + p_ * 8;   // + m*512
  const int fB  = wc * 2048 + (fr >> 1) * 64 + p_ * 8;   // + n*512

#define STAGE(buf, kt) do {                                                     \
    const size_t kb_ = (size_t)(kt) * 32 + colg;                                \
    GLOAD16(Ab + (size_t)(wave * 16 + rloc) * lda + kb_,      &As[buf][wave * 512]);       \
    GLOAD16(Ab + (size_t)(64 + wave * 16 + rloc) * lda + kb_, &As[buf][(wave + 4) * 512]); \
    GLOAD16(Bb + (size_t)(wave * 16 + rloc) * ldb + kb_,      &Bs[buf][wave * 512]);       \
    GLOAD16(Bb + (size_t)(64 + wave * 16 + rloc) * ldb + kb_, &Bs[buf][(wave + 4) * 512]); \
  } while (0)

  // prologue: tiles 0 and 1 in flight; wait tile0 (leave tile1's 4 loads)
  STAGE(0, 0);
  STAGE(1, 1);                                  // all modes have ktiles >= 4
  asm volatile("s_waitcnt vmcnt(4)" ::: "memory");
  __builtin_amdgcn_s_barrier();
  __builtin_amdgcn_sched_barrier(0);

  for (int kt = 0; kt < ktiles; ++kt) {
    const int cur = kt % 3;
    if (kt + 2 < ktiles) STAGE((kt + 2) % 3, kt + 2);

    bf16x8 af[4], bfv[4];
#pragma unroll
    for (int mi = 0; mi < 4; ++mi)
      af[mi] = *reinterpret_cast<const bf16x8*>(&As[cur][fA + mi * 512]);
#pragma unroll
    for (int ni = 0; ni < 4; ++ni)
      bfv[ni] = *reinterpret_cast<const bf16x8*>(&Bs[cur][fB + ni * 512]);

    __builtin_amdgcn_s_setprio(1);
#pragma unroll
    for (int mi = 0; mi < 4; ++mi)
#pragma unroll
      for (int ni = 0; ni < 4; ++ni)
        acc[mi][ni] = __builtin_amdgcn_mfma_f32_16x16x32_bf16(af[mi], bfv[ni], acc[mi][ni], 0, 0, 0);
    __builtin_amdgcn_s_setprio(0);

    // drain tile kt+1's loads only (tile kt+2's 4 remain in flight), then join.
    asm volatile("s_waitcnt vmcnt(4)" ::: "memory");
    __builtin_amdgcn_s_barrier();
    __builtin_amdgcn_sched_barrier(0);
  }
#undef STAGE

  // epilogue: C/D layout col = lane&15, row = (lane>>4)*4 + r
  const int row0 = wr * 64, col0 = wc * 64;
  const float* bp = bias0;
  if constexpr (MODE == 0) bp = (tj < 8) ? bias0 : ((tj < 16) ? bias1 : bias2);
#pragma unroll
  for (int mi = 0; mi < 4; ++mi) {
#pragma unroll
    for (int ni = 0; ni < 4; ++ni) {
#pragma unroll
      for (int r = 0; r < 4; ++r) {
        const int lr = row0 + mi * 16 + (lane >> 4) * 4 + r;
        const int lc = col0 + ni * 16 + (lane & 15);
        const float v = acc[mi][ni][r];
        if constexpr (MODE == 0) {
          const int gr = ti * 128 + lr, gc = tj * 128 + lc;
          ((unsigned short*)C)[(size_t)gr * QKVN + gc] = f2bf(v + bp[gc & 1023]);
        } else if constexpr (MODE == 1) {
          const int gr = ti * 128 + lr, gc = tj * 128 + lc;
          ((float*)C)[(size_t)gr * DDIM + gc] = v + bp[gc];
        } else if constexpr (MODE == 2) {
          const int gi = ti * 128 + lr, gj = tj * 128 + lc;
          float s = fabsf(v) * 0.03125f;            // |q.k| / sqrt(1024)
          if (gj > gi) s = -INFINITY;               // strictly-above diag (diag tiles)
          ((unsigned short*)C)[(size_t)bz * SDIM * SDIM + (size_t)gi * SDIM + gj] = f2bf(s);
        } else {
          const int gi = ti * 128 + lr, gd = tj * 128 + lc;
          ((unsigned short*)C)[(size_t)bz * SDIM * DDIM + (size_t)gi * DDIM + gd] = f2bf(v);
        }
      }
    }
  }
}

// ---------------- one-pass vectorized row softmax ----------------
// Row i: entries [0, L=i+1) are |s|>=0; [L, Lpad) are -inf (from MODE 2
// diagonal tiles) -> exp gives exact 0, which MODE 3 requires for padding.
__global__ void softmax_rows(unsigned short* __restrict__ Sc) {
  const int rid = blockIdx.x;            // 0 .. BATCH*SDIM-1
  const int b = rid >> 11, i = rid & (SDIM - 1);
  unsigned short* row = Sc + ((size_t)b * SDIM + i) * SDIM;
  const int Lpad = ((i >> 7) + 1) << 7;  // next 128 boundary
  const int tid  = threadIdx.x;
  const bool act = tid * 8 < Lpad;

  float v[8];
  float m = 0.0f;                        // row max >= 0 always
  if (act) {
    u16x8 u = *reinterpret_cast<const u16x8*>(row + tid * 8);
#pragma unroll
    for (int e = 0; e < 8; ++e) { v[e] = bf2f(u[e]); m = fmaxf(m, v[e]); }
  }
#pragma unroll
  for (int off = 32; off; off >>= 1) m = fmaxf(m, __shfl_down(m, off));
  __shared__ float redm[4], reds[4];
  if ((tid & 63) == 0) redm[tid >> 6] = m;
  __syncthreads();
  const float M = fmaxf(fmaxf(redm[0], redm[1]), fmaxf(redm[2], redm[3]));

  float s = 0.0f;
  if (act) {
#pragma unroll
    for (int e = 0; e < 8; ++e) { v[e] = expf(v[e] - M); s += v[e]; }  // -inf -> 0
  }
#pragma unroll
  for (int off = 32; off; off >>= 1) s += __shfl_down(s, off);
  if ((tid & 63) == 0) reds[tid >> 6] = s;
  __syncthreads();
  const float inv = 1.0f / (reds[0] + reds[1] + reds[2] + reds[3]);

  if (act) {
    ushort4 o0, o1;
    o0.x = f2bf(v[0] * inv); o0.y = f2bf(v[1] * inv);
    o0.z = f2bf(v[2] * inv); o0.w = f2bf(v[3] * inv);
    o1.x = f2bf(v[4] * inv); o1.y = f2bf(v[5] * inv);
    o1.z = f2bf(v[6] * inv); o1.w = f2bf(v[7] * inv);
    *reinterpret_cast<ushort4*>(row + tid * 8)     = o0;
    *reinterpret_cast<ushort4*>(row + tid * 8 + 4) = o1;
  }
}

// ---------------- bf16 transpose: V section of QKVb -> Vt[B,1024,2048] ----------------
__global__ void transpose_v(const unsigned short* __restrict__ qkv,
                            unsigned short* __restrict__ out) {
  __shared__ unsigned short tile[64][65];
  const int b = blockIdx.z;
  const unsigned short* in = qkv + (size_t)b * SDIM * QKVN + 2048;  // V section
  unsigned short* o = out + (size_t)b * DDIM * SDIM;
  const int tx = threadIdx.x & 63;
  const int ty = threadIdx.x >> 6;
  const int r0 = blockIdx.y * 64;   // token tile
  const int c0 = blockIdx.x * 64;   // v-dim tile
  for (int r = ty; r < 64; r += 4)
    tile[r][tx] = in[(size_t)(r0 + r) * QKVN + c0 + tx];
  __syncthreads();
  for (int r = ty; r < 64; r += 4)
    o[(size_t)(c0 + r) * SDIM + r0 + tx] = tile[tx][r];
}

// ---------------- host launch ----------------
extern "C" void kernel_launch(void* const* d_in, const int* in_sizes, int n_in,
                              void* d_out, int out_size, void* d_ws, size_t ws_size,
                              hipStream_t stream) {
  const float* x  = (const float*)d_in[0];
  const float* Wq = (const float*)d_in[1];
  const float* bq = (const float*)d_in[2];
  const float* Wk = (const float*)d_in[3];
  const float* bk = (const float*)d_in[4];
  const float* Wv = (const float*)d_in[5];
  const float* bv = (const float*)d_in[6];
  const float* Wo = (const float*)d_in[7];
  const float* bo = (const float*)d_in[8];
  float* out = (float*)d_out;

  const size_t NTOK = (size_t)BATCH * SDIM;       // 8192
  unsigned short* ws = (unsigned short*)d_ws;
  unsigned short* xb   = ws;                          // [8192,1024]
  unsigned short* wqkv = xb + NTOK * DDIM;            // [3072,1024]
  unsigned short* wo   = wqkv + (size_t)QKVN * DDIM;  // [1024,1024] (contiguous after wqkv)
  unsigned short* QKVb = wo + (size_t)DDIM * DDIM;    // [8192,3072]
  unsigned short* Vt   = QKVb + NTOK * QKVN;          // [B,1024,2048]
  unsigned short* Ob   = Vt + NTOK * DDIM;            // [8192,1024]
  unsigned short* Sc   = Ob + NTOK * DDIM;            // [B,2048,2048]

  const int NX = (int)(NTOK * DDIM);              // 8M

  cvt_f32_bf16<<<2048, 256, 0, stream>>>(x, xb, NX);
  cvt_weights<<<dim3(256, 4), 256, 0, stream>>>(Wq, Wk, Wv, Wo, wqkv);  // wo follows wqkv

  // fused QKV projection -> QKVb [8192, 3072]
  gemm_kernel<0><<<dim3(64, 24), 256, 0, stream>>>(xb, wqkv, bq, bk, bv, QKVb);

  // scores (lower-triangular tiles): Sc = bf16(|Q@K^T|/32), -inf above diag
  gemm_kernel<2><<<dim3(136, BATCH), 256, 0, stream>>>(QKVb, nullptr, nullptr, nullptr, nullptr, Sc);

  // one-pass softmax (in place; padding becomes exact 0)
  softmax_rows<<<BATCH * SDIM, 256, 0, stream>>>(Sc);

  // V transpose for NT PV gemm
  transpose_v<<<dim3(DDIM / 64, SDIM / 64, BATCH), 256, 0, stream>>>(QKVb, Vt);

  // O = P @ V (causal-truncated K)
  gemm_kernel<3><<<dim3(128, BATCH), 256, 0, stream>>>(Sc, Vt, nullptr, nullptr, nullptr, Ob);

  // final projection -> fp32 out
  gemm_kernel<1><<<dim3(64, 8), 256, 0, stream>>>(Ob, wo, bo, nullptr, nullptr, out);
}